// Round 18
// baseline (233.883 us; speedup 1.0000x reference)
//
#include <hip/hip_runtime.h>
#include <hip/hip_bf16.h>

typedef __attribute__((ext_vector_type(4)))  float  f32x4;
typedef __attribute__((ext_vector_type(8)))  __bf16 bf16x8;
typedef __attribute__((ext_vector_type(4)))  __bf16 bf16x4;

#define LOG2E_O16 0.09016844005556021f  // log2(e)/16  (scale = 1/sqrt(256))

__device__ __forceinline__ void gload_lds16(const void* g, void* l) {
  __builtin_amdgcn_global_load_lds(
      (const __attribute__((address_space(1))) void*)g,
      (__attribute__((address_space(3))) void*)l, 16, 0, 0);
}

// ---------------- X = GA[g,n] * rep_R, fp32 -> bf16 ----------------
__global__ __launch_bounds__(256) void scale_kernel(
    const float* __restrict__ rep, const float* __restrict__ GA, __bf16* __restrict__ X)
{
  size_t i = (size_t)blockIdx.x * 256 + threadIdx.x;
  size_t e = i * 4;
  f32x4 r = *(const f32x4*)(rep + e);
  int dn = (int)(e >> 8);
  int n  = dn & 511;
  int g  = (dn >> 9) & 15;
  float ga = GA[g * 512 + n];
  bf16x4 o;
  o[0] = (__bf16)(r[0] * ga); o[1] = (__bf16)(r[1] * ga);
  o[2] = (__bf16)(r[2] * ga); o[3] = (__bf16)(r[3] * ga);
  *(bf16x4*)(X + e) = o;
}

// ---------------- weight convert: ten 256x256 fp32 w[K][N] -> bf16 wT[N][K] ----------------
struct WPtrs { const float* w[10]; };
__global__ __launch_bounds__(256) void wconv_kernel(WPtrs ws, __bf16* __restrict__ out)
{
  __shared__ float t[64][65];
  const float* w = ws.w[blockIdx.y];
  __bf16* o = out + (size_t)blockIdx.y * 65536;
  const int tr = (blockIdx.x & 3) * 64, tc = (blockIdx.x >> 2) * 64;
  const int r4 = threadIdx.x >> 6, c = threadIdx.x & 63;
#pragma unroll
  for (int p = 0; p < 16; ++p) {
    int row = p * 4 + r4;
    t[row][c] = w[(size_t)(tr + row) * 256 + tc + c];
  }
  __syncthreads();
#pragma unroll
  for (int p = 0; p < 16; ++p) {
    int row = p * 4 + r4;
    o[(size_t)(tc + row) * 256 + tr + c] = (__bf16)t[c][row];
  }
}

// ======== 2-phase pipelined BK=64 tile body (128x128 tile, 4 waves, dbuf LDS) ========
#define STAGE_T(A_, B_, bmv, bnv, Kv, tt, bb) do {                                 \
    _Pragma("unroll")                                                              \
    for (int r = 0; r < 4; ++r) {                                                  \
      int rowl = r * 32 + (tid >> 3);                                              \
      int sl = (tid & 7) ^ (rowl & 7);                                             \
      gload_lds16((const char*)((A_) + (size_t)((bmv) + rowl) * (Kv) + (tt) * 64) + sl * 16, \
                  (char*)sA + (bb) * 16384 + r * 4096 + wv * 1024);                \
      gload_lds16((const char*)((B_) + (size_t)((bnv) + rowl) * (Kv) + (tt) * 64) + sl * 16, \
                  (char*)sB + (bb) * 16384 + r * 4096 + wv * 1024);                \
    } } while (0)

#define GEMM64_PIPE(A_, B_, bmv, bnv, Kv)                                          \
  f32x4 acc[4][4] = {};                                                            \
  const int nt = (Kv) >> 6;                                                        \
  STAGE_T(A_, B_, bmv, bnv, Kv, 0, 0);                                             \
  asm volatile("s_waitcnt vmcnt(0)" ::: "memory");                                 \
  __builtin_amdgcn_s_barrier();                                                    \
  for (int t = 0; t < nt; ++t) {                                                   \
    if (t + 1 < nt) STAGE_T(A_, B_, bmv, bnv, Kv, t + 1, (t + 1) & 1);             \
    const char* bA = (const char*)sA + (t & 1) * 16384;                            \
    const char* bB = (const char*)sB + (t & 1) * 16384;                            \
    bf16x8 af[4][2], bfr[4][2];                                                    \
    _Pragma("unroll")                                                              \
    for (int mi = 0; mi < 4; ++mi) {                                               \
      int row = wr + mi * 16 + l16;                                                \
      _Pragma("unroll")                                                            \
      for (int kk = 0; kk < 2; ++kk) {                                             \
        int sl = (kk * 4 + lg) ^ (row & 7);                                        \
        af[mi][kk] = *(const bf16x8*)(bA + row * 128 + sl * 16);                   \
      }                                                                            \
    }                                                                              \
    _Pragma("unroll")                                                              \
    for (int ni = 0; ni < 4; ++ni) {                                               \
      int row = wc + ni * 16 + l16;                                                \
      _Pragma("unroll")                                                            \
      for (int kk = 0; kk < 2; ++kk) {                                             \
        int sl = (kk * 4 + lg) ^ (row & 7);                                        \
        bfr[ni][kk] = *(const bf16x8*)(bB + row * 128 + sl * 16);                  \
      }                                                                            \
    }                                                                              \
    _Pragma("unroll")                                                              \
    for (int kk = 0; kk < 2; ++kk)                                                 \
      _Pragma("unroll")                                                            \
      for (int mi = 0; mi < 4; ++mi)                                               \
        _Pragma("unroll")                                                          \
        for (int ni = 0; ni < 4; ++ni)                                             \
          acc[mi][ni] = __builtin_amdgcn_mfma_f32_16x16x32_bf16(                   \
              af[mi][kk], bfr[ni][kk], acc[mi][ni], 0, 0, 0);                      \
    asm volatile("s_waitcnt vmcnt(0)" ::: "memory");                               \
    __builtin_amdgcn_s_barrier();                                                  \
  }

// ---------------- fused multi-output GEMM: out[j] = A @ Bt[j]^T + bias[j] ----------------
struct QKV3 {
  const __bf16* Bt[3];
  const float* bias[3];
  __bf16* out[3];
};

template<int NW>
__global__ __launch_bounds__(256) void gemmqkv_kernel(
    const __bf16* __restrict__ A, QKV3 args, int K)
{
  __shared__ __align__(16) __bf16 smem[32768];   // 64 KB: sA dbuf | sB dbuf; reused as sC
  __bf16* const sA = smem;
  __bf16* const sB = smem + 16384;
  __bf16* const sC = smem;                       // 128 x 136 bf16 epilogue tile
  const int tid = threadIdx.x, lane = tid & 63, wv = tid >> 6;
  const int l16 = lane & 15, lg = lane >> 4;
  const int wr = (wv >> 1) * 64, wc = (wv & 1) * 64;

  const int nblk = gridDim.x, cpx = nblk >> 3, orig = blockIdx.x;
  const int wg  = (orig & 7) * cpx + (orig >> 3);       // bijective XCD swizzle
  const int r_  = wg / (2 * NW), rem = wg % (2 * NW);
  const int j   = rem >> 1;
  const int bm  = r_ * 128, bn = (rem & 1) * 128;
  const __bf16* __restrict__ Bt = args.Bt[j];

  GEMM64_PIPE(A, Bt, bm, bn, K)

  const float* bias = args.bias[j];
  __bf16* C = args.out[j];
#pragma unroll
  for (int mi = 0; mi < 4; ++mi)
#pragma unroll
    for (int ni = 0; ni < 4; ++ni) {
      int cl = wc + ni * 16 + l16;
      float bval = bias[bn + cl];
      int r0 = wr + mi * 16 + lg * 4;
#pragma unroll
      for (int i = 0; i < 4; ++i)
        sC[(r0 + i) * 136 + cl] = (__bf16)(acc[mi][ni][i] + bval);
    }
  __syncthreads();
#pragma unroll
  for (int it = 0; it < 8; ++it) {
    int idx = it * 256 + tid;
    int r = idx >> 4, seg = idx & 15;
    bf16x8 cv = *(const bf16x8*)&sC[r * 136 + seg * 8];
    *(bf16x8*)(C + (size_t)(bm + r) * 256 + bn + seg * 8) = cv;
  }
}

// ---------------- O-proj GEMM: C = R + relu(A @ Bt^T + bias) ----------------
__global__ __launch_bounds__(256) void gemm128_kernel(
    const __bf16* __restrict__ A, const __bf16* __restrict__ Bt,
    const float* __restrict__ bias, const __bf16* __restrict__ R,
    __bf16* __restrict__ C, int K)
{
  __shared__ __align__(16) __bf16 smem[32768];
  __bf16* const sA = smem;
  __bf16* const sB = smem + 16384;
  __bf16* const sC = smem;
  const int tid = threadIdx.x, lane = tid & 63, wv = tid >> 6;
  const int l16 = lane & 15, lg = lane >> 4;
  const int wr = (wv >> 1) * 64, wc = (wv & 1) * 64;

  const int nblk = gridDim.x, cpx = nblk >> 3, orig = blockIdx.x;
  const int wg  = (orig & 7) * cpx + (orig >> 3);
  const int bm  = (wg >> 1) * 128, bn = (wg & 1) * 128;

  GEMM64_PIPE(A, Bt, bm, bn, K)

  const float* __restrict__ biasp = bias;
#pragma unroll
  for (int mi = 0; mi < 4; ++mi)
#pragma unroll
    for (int ni = 0; ni < 4; ++ni) {
      int cl = wc + ni * 16 + l16;
      float bval = biasp[bn + cl];
      int r0 = wr + mi * 16 + lg * 4;
#pragma unroll
      for (int i = 0; i < 4; ++i)
        sC[(r0 + i) * 136 + cl] = (__bf16)fmaxf(acc[mi][ni][i] + bval, 0.f);
    }
  __syncthreads();
#pragma unroll
  for (int it = 0; it < 8; ++it) {
    int idx = it * 256 + tid;
    int r = idx >> 4, seg = idx & 15;
    bf16x8 cv = *(const bf16x8*)&sC[r * 136 + seg * 8];
    bf16x8 rv = *(const bf16x8*)(R + (size_t)(bm + r) * 256 + bn + seg * 8);
    bf16x8 ov;
#pragma unroll
    for (int i = 0; i < 8; ++i)
      ov[i] = (__bf16)((float)rv[i] + (float)cv[i]);
    *(bf16x8*)(C + (size_t)(bm + r) * 256 + bn + seg * 8) = ov;
  }
}

// ---------------- fused SAB attention (R13/R14 artifact, final) ----------------
__global__ __launch_bounds__(512, 2) void attn_sab_kernel(
    __bf16* __restrict__ Q, const __bf16* __restrict__ Kb, const __bf16* __restrict__ Vb)
{
  __shared__ __align__(16) __bf16 sK[128][72];
  __shared__ __align__(16) __bf16 sV[64][136];
  __shared__ __align__(16) __bf16 sP[8][16][72];

  const int orig = blockIdx.x;                 // 512 blocks
  const int wg   = (orig & 7) * 64 + (orig >> 3);
  const int qh   = wg & 1;
  const int pair = wg >> 1;                    // 0..255
  const int head = pair & 3;
  const int item = pair >> 2;

  const int tid  = threadIdx.x;
  const int lane = tid & 63;
  const int wv   = tid >> 6;
  const int l16  = lane & 15;
  const int lg   = lane >> 4;
  const size_t base = (size_t)item * (512 * 256) + (size_t)head * 64;
  const int qrow0 = qh * 256 + wv * 32;

  // hoisted Q fragments: [qb][d-half]
  bf16x8 aq[2][2];
#pragma unroll
  for (int qb = 0; qb < 2; ++qb) {
    const size_t qrow = base + (size_t)(qrow0 + qb * 16 + l16) * 256;
    aq[qb][0] = *(const bf16x8*)(Q + qrow + lg * 8);
    aq[qb][1] = *(const bf16x8*)(Q + qrow + 32 + lg * 8);
  }

  f32x4 acco[2][4] = {};
  float lsum[2] = {0.f, 0.f};

  const int kr  = tid >> 3, kc8 = (tid & 7) * 8;
  const int vch = tid & 63, vk8 = (tid >> 6) * 8;

  bf16x8 kreg[2], vreg[2];

#define LOADC(cc) do {                                                             \
    _Pragma("unroll")                                                              \
    for (int p = 0; p < 2; ++p) {                                                  \
      kreg[p] = *(const bf16x8*)(Kb + base + (size_t)((cc)*128 + p*64 + kr)*256 + kc8); \
      bf16x8 vv;                                                                   \
      _Pragma("unroll")                                                            \
      for (int jj = 0; jj < 8; ++jj)                                               \
        vv[jj] = Vb[base + (size_t)((cc)*128 + p*64 + vk8 + jj)*256 + vch];        \
      vreg[p] = vv;                                                                \
    } } while (0)

  LOADC(0);

  for (int c = 0; c < 4; ++c) {
    if (c) __syncthreads();                    // all waves done reading prev chunk
#pragma unroll
    for (int p = 0; p < 2; ++p) {
      *(bf16x8*)&sK[p * 64 + kr][kc8] = kreg[p];
      *(bf16x8*)&sV[vch][p * 64 + vk8] = vreg[p];
    }
    __syncthreads();
    if (c < 3) LOADC(c + 1);                   // overlaps with compute below

#pragma unroll
    for (int half = 0; half < 2; ++half) {
      // K-frags and V-frags for this 64-key half: loaded once, reused by both q-tiles
      bf16x8 kf0[4], kf1[4];
#pragma unroll
      for (int st = 0; st < 4; ++st) {
        int krl = half * 64 + st * 16 + l16;
        kf0[st] = *(const bf16x8*)&sK[krl][lg * 8];
        kf1[st] = *(const bf16x8*)&sK[krl][32 + lg * 8];
      }
      bf16x8 vf[2][4];
#pragma unroll
      for (int kk = 0; kk < 2; ++kk)
#pragma unroll
        for (int vt = 0; vt < 4; ++vt)
          vf[kk][vt] = *(const bf16x8*)&sV[vt * 16 + l16][half * 64 + kk * 32 + lg * 8];

#pragma unroll
      for (int qb = 0; qb < 2; ++qb) {
        f32x4 s[4];
#pragma unroll
        for (int st = 0; st < 4; ++st) {
          f32x4 z = {};
          s[st] = __builtin_amdgcn_mfma_f32_16x16x32_bf16(kf0[st], aq[qb][0], z, 0, 0, 0);
        }
#pragma unroll
        for (int st = 0; st < 4; ++st)
          s[st] = __builtin_amdgcn_mfma_f32_16x16x32_bf16(kf1[st], aq[qb][1], s[st], 0, 0, 0);
#pragma unroll
        for (int st = 0; st < 4; ++st) {
          bf16x4 pv4;
          float ls = 0.f;
#pragma unroll
          for (int i = 0; i < 4; ++i) {
            float p = __builtin_amdgcn_exp2f(s[st][i] * LOG2E_O16);
            ls += p;
            pv4[i] = (__bf16)p;
          }
          lsum[qb] += ls;
          *(bf16x4*)&sP[wv][l16][st * 16 + lg * 4] = pv4;
        }
#pragma unroll
        for (int kk = 0; kk < 2; ++kk) {
          bf16x8 ap = *(const bf16x8*)&sP[wv][l16][kk * 32 + lg * 8];
#pragma unroll
          for (int vt = 0; vt < 4; ++vt)
            acco[qb][vt] = __builtin_amdgcn_mfma_f32_16x16x32_bf16(ap, vf[kk][vt], acco[qb][vt], 0, 0, 0);
        }
      }
    }
  }
#undef LOADC

#pragma unroll
  for (int qb = 0; qb < 2; ++qb) {
    float t = lsum[qb];
    t += __shfl_xor(t, 16, 64);
    t += __shfl_xor(t, 32, 64);
#pragma unroll
    for (int i = 0; i < 4; ++i) {
      float tot = __shfl(t, lg * 4 + i, 64);
      float inv = 1.0f / tot;
      int row = qrow0 + qb * 16 + lg * 4 + i;
#pragma unroll
      for (int vt = 0; vt < 4; ++vt) {
        size_t idx = base + (size_t)row * 256 + vt * 16 + l16;
        Q[idx] = (__bf16)((float)Q[idx] + acco[qb][vt][i] * inv);
      }
    }
  }
}

// ---------------- PMA decode attention v2: grid 256 = (item, quarter) ----------------
__global__ __launch_bounds__(256) void pma_attn_kernel(
    const float* __restrict__ S, const float* __restrict__ wq,
    const float* __restrict__ bq, const __bf16* __restrict__ Kb,
    const __bf16* __restrict__ Vb, __bf16* __restrict__ Opma)
{
  __shared__ float sS[256];
  __shared__ float sq[256];
  __shared__ float sP[512];      // this head's scores
  __shared__ float wsum[4];
  __shared__ float sl0;
  __shared__ float red[256];

  const int item = blockIdx.x >> 2;
  const int quarter = blockIdx.x & 3;
  const int h = quarter >> 1;
  const int t = threadIdx.x;
  const int lane = t & 63, wv = t >> 6;

  sS[t] = S[t];
  __syncthreads();
  {
    float acc = bq[t];
#pragma unroll 8
    for (int k = 0; k < 256; ++k) acc += sS[k] * wq[k * 256 + t];
    sq[t] = acc;
  }
  __syncthreads();

  // QK for head h: 512 keys, 2 per thread
#pragma unroll
  for (int rep = 0; rep < 2; ++rep) {
    int key = rep * 256 + t;
    const __bf16* kr = Kb + ((size_t)item * 512 + key) * 256 + h * 128;
    float s = 0.f;
#pragma unroll
    for (int d8 = 0; d8 < 128; d8 += 8) {
      bf16x8 kv = *(const bf16x8*)(kr + d8);
#pragma unroll
      for (int j = 0; j < 8; ++j) s += sq[h * 128 + d8 + j] * (float)kv[j];
    }
    sP[key] = __builtin_amdgcn_exp2f(s * LOG2E_O16);
  }
  __syncthreads();

  // denominator: wave shfl reduce + cross-wave
  {
    float p = sP[t] + sP[t + 256];
#pragma unroll
    for (int m = 1; m < 64; m <<= 1) p += __shfl_xor(p, m, 64);
    if (lane == 0) wsum[wv] = p;
  }
  __syncthreads();
  if (t == 0) sl0 = 1.0f / (wsum[0] + wsum[1] + wsum[2] + wsum[3]);

  // PV: 64 channels (quarter*64 + chl), 4 threads/channel x 128 keys
  {
    const int chl = t & 63, seg = t >> 6;
    const int ch = quarter * 64 + chl;
    const __bf16* vp = Vb + ((size_t)item * 512 + seg * 128) * 256 + ch;
    float acc = 0.f;
#pragma unroll 4
    for (int k = 0; k < 128; ++k)
      acc += sP[seg * 128 + k] * (float)vp[(size_t)k * 256];
    red[t] = acc;
  }
  __syncthreads();
  if (t < 64) {
    int ch = quarter * 64 + t;
    float a = red[t] + red[t + 64] + red[t + 128] + red[t + 192];
    Opma[item * 256 + ch] = (__bf16)(sq[ch] + a * sl0);
  }
}

// ---------------- fused tail: per item, O-proj(+resid+relu) -> MLP1 -> MLP2 -> MLP3 ----
// grid 64 (one block per item), 512 threads, all fp32. Weights L2/L3-resident.
__global__ __launch_bounds__(512) void mlp_fused_kernel(
    const __bf16* __restrict__ Opma,
    const float* __restrict__ wo, const float* __restrict__ bo,
    const float* __restrict__ w1, const float* __restrict__ b1,
    const float* __restrict__ w2, const float* __restrict__ b2,
    const float* __restrict__ w3, const float* __restrict__ b3,
    float* __restrict__ out)
{
  __shared__ float xO[256];     // O (pma output row)
  __shared__ float xO2[256];    // O + relu(O@wo+bo)
  __shared__ float h1[512];
  __shared__ float h2[512];
  __shared__ float part[512];

  const int item = blockIdx.x;
  const int t = threadIdx.x;            // 0..511

  if (t < 256) xO[t] = (float)Opma[item * 256 + t];
  __syncthreads();

  // O-proj: 256 outputs; k split across thread pairs (t, t+256)
  {
    const int j = t & 255, kh = t >> 8;
    float s = 0.f;
#pragma unroll 8
    for (int k = kh * 128; k < kh * 128 + 128; ++k)
      s += xO[k] * wo[(size_t)k * 256 + j];
    part[t] = s;
  }
  __syncthreads();
  if (t < 256) {
    float v = part[t] + part[t + 256] + bo[t];
    xO2[t] = xO[t] + fmaxf(v, 0.f);
  }
  __syncthreads();

  // MLP1: h1 = relu(xO2 @ w1 + b1), 512 outputs, k=256
  {
    float s = b1[t];
#pragma unroll 8
    for (int k = 0; k < 256; ++k)
      s += xO2[k] * w1[(size_t)k * 512 + t];
    h1[t] = fmaxf(s, 0.f);
  }
  __syncthreads();

  // MLP2: h2 = relu(h1 @ w2 + b2), 512 outputs, k=512
  {
    float s = b2[t];
#pragma unroll 8
    for (int k = 0; k < 512; ++k)
      s += h1[k] * w2[(size_t)k * 512 + t];
    h2[t] = fmaxf(s, 0.f);
  }
  __syncthreads();

  // MLP3: out = h2 @ w3 + b3, 256 outputs, k=512 split across thread pairs
  {
    const int j = t & 255, kh = t >> 8;
    float s = 0.f;
#pragma unroll 8
    for (int k = kh * 256; k < kh * 256 + 256; ++k)
      s += h2[k] * w3[(size_t)k * 256 + j];
    part[t] = s;
  }
  __syncthreads();
  if (t < 256)
    out[item * 256 + t] = part[t] + part[t + 256] + b3[t];
}

// ---------------- launch ----------------
extern "C" void kernel_launch(void* const* d_in, const int* in_sizes, int n_in,
                              void* d_out, int out_size, void* d_ws, size_t ws_size,
                              hipStream_t stream)
{
  const size_t XSZ = (size_t)64 * 512 * 256;
  if (ws_size < 4 * XSZ * sizeof(__bf16) + (4u << 20)) return;

  const float* rep = (const float*)d_in[0];
  const float* GA  = (const float*)d_in[1];

  __bf16* X    = (__bf16*)d_ws;
  __bf16* Qb   = X  + XSZ;
  __bf16* Kb   = Qb + XSZ;
  __bf16* Vb   = Kb + XSZ;
  __bf16* wT   = Vb + XSZ;                 // 10 x 256x256 bf16 (row = out ch, col = k)
  __bf16* Opma = wT + 10 * 65536;

  WPtrs wp;
  for (int s = 0; s < 2; ++s)
    for (int j = 0; j < 4; ++j)
      wp.w[s * 4 + j] = (const float*)d_in[2 + s * 8 + j * 2];
  wp.w[8] = (const float*)d_in[21];
  wp.w[9] = (const float*)d_in[23];
  wconv_kernel<<<dim3(16, 10), 256, 0, stream>>>(wp, wT);

  scale_kernel<<<8192, 256, 0, stream>>>(rep, GA, X);

  for (int sab = 0; sab < 2; ++sab) {
    QKV3 a;
    a.Bt[0] = wT + (size_t)(sab * 4 + 0) * 65536;
    a.Bt[1] = wT + (size_t)(sab * 4 + 1) * 65536;
    a.Bt[2] = wT + (size_t)(sab * 4 + 2) * 65536;
    a.bias[0] = (const float*)d_in[2 + sab * 8 + 1];
    a.bias[1] = (const float*)d_in[2 + sab * 8 + 3];
    a.bias[2] = (const float*)d_in[2 + sab * 8 + 5];
    a.out[0] = Qb; a.out[1] = Kb; a.out[2] = Vb;
    gemmqkv_kernel<3><<<1536, 256, 0, stream>>>(X, a, 256);
    attn_sab_kernel<<<512, 512, 0, stream>>>(Qb, Kb, Vb);
    gemm128_kernel<<<512, 256, 0, stream>>>(Qb, wT + (size_t)(sab * 4 + 3) * 65536,
        (const float*)d_in[2 + sab * 8 + 7], Qb, X, 256);
  }

  {
    QKV3 a;
    a.Bt[0] = wT + (size_t)8 * 65536;
    a.Bt[1] = wT + (size_t)9 * 65536;
    a.Bt[2] = wT;  // unused
    a.bias[0] = (const float*)d_in[22];
    a.bias[1] = (const float*)d_in[24];
    a.bias[2] = (const float*)d_in[22];  // unused
    a.out[0] = Kb; a.out[1] = Vb; a.out[2] = Kb;  // slot 2 unused
    gemmqkv_kernel<2><<<1024, 256, 0, stream>>>(X, a, 256);
  }
  pma_attn_kernel<<<256, 256, 0, stream>>>((const float*)d_in[18], (const float*)d_in[19],
      (const float*)d_in[20], Kb, Vb, Opma);
  mlp_fused_kernel<<<64, 512, 0, stream>>>(Opma,
      (const float*)d_in[25], (const float*)d_in[26],
      (const float*)d_in[27], (const float*)d_in[28],
      (const float*)d_in[29], (const float*)d_in[30],
      (const float*)d_in[31], (const float*)d_in[32],
      (float*)d_out);
}

// Round 19
// 214.148 us; speedup vs baseline: 1.0922x; 1.0922x over previous
//
#include <hip/hip_runtime.h>
#include <hip/hip_bf16.h>

typedef __attribute__((ext_vector_type(4)))  float  f32x4;
typedef __attribute__((ext_vector_type(8)))  __bf16 bf16x8;
typedef __attribute__((ext_vector_type(4)))  __bf16 bf16x4;

#define LOG2E_O16 0.09016844005556021f  // log2(e)/16  (scale = 1/sqrt(256))

__device__ __forceinline__ void gload_lds16(const void* g, void* l) {
  __builtin_amdgcn_global_load_lds(
      (const __attribute__((address_space(1))) void*)g,
      (__attribute__((address_space(3))) void*)l, 16, 0, 0);
}

// ---------------- X = GA[g,n] * rep_R, fp32 -> bf16 ----------------
__global__ __launch_bounds__(256) void scale_kernel(
    const float* __restrict__ rep, const float* __restrict__ GA, __bf16* __restrict__ X)
{
  size_t i = (size_t)blockIdx.x * 256 + threadIdx.x;
  size_t e = i * 4;
  f32x4 r = *(const f32x4*)(rep + e);
  int dn = (int)(e >> 8);
  int n  = dn & 511;
  int g  = (dn >> 9) & 15;
  float ga = GA[g * 512 + n];
  bf16x4 o;
  o[0] = (__bf16)(r[0] * ga); o[1] = (__bf16)(r[1] * ga);
  o[2] = (__bf16)(r[2] * ga); o[3] = (__bf16)(r[3] * ga);
  *(bf16x4*)(X + e) = o;
}

// ---------------- weight convert: ten 256x256 fp32 w[K][N] -> bf16 wT[N][K] ----------------
struct WPtrs { const float* w[10]; };
__global__ __launch_bounds__(256) void wconv_kernel(WPtrs ws, __bf16* __restrict__ out)
{
  __shared__ float t[64][65];
  const float* w = ws.w[blockIdx.y];
  __bf16* o = out + (size_t)blockIdx.y * 65536;
  const int tr = (blockIdx.x & 3) * 64, tc = (blockIdx.x >> 2) * 64;
  const int r4 = threadIdx.x >> 6, c = threadIdx.x & 63;
#pragma unroll
  for (int p = 0; p < 16; ++p) {
    int row = p * 4 + r4;
    t[row][c] = w[(size_t)(tr + row) * 256 + tc + c];
  }
  __syncthreads();
#pragma unroll
  for (int p = 0; p < 16; ++p) {
    int row = p * 4 + r4;
    o[(size_t)(tc + row) * 256 + tr + c] = (__bf16)t[c][row];
  }
}

// ======== 2-phase pipelined BK=64 tile body (128x128 tile, 4 waves, dbuf LDS) ========
#define STAGE_T(A_, B_, bmv, bnv, Kv, tt, bb) do {                                 \
    _Pragma("unroll")                                                              \
    for (int r = 0; r < 4; ++r) {                                                  \
      int rowl = r * 32 + (tid >> 3);                                              \
      int sl = (tid & 7) ^ (rowl & 7);                                             \
      gload_lds16((const char*)((A_) + (size_t)((bmv) + rowl) * (Kv) + (tt) * 64) + sl * 16, \
                  (char*)sA + (bb) * 16384 + r * 4096 + wv * 1024);                \
      gload_lds16((const char*)((B_) + (size_t)((bnv) + rowl) * (Kv) + (tt) * 64) + sl * 16, \
                  (char*)sB + (bb) * 16384 + r * 4096 + wv * 1024);                \
    } } while (0)

#define GEMM64_PIPE(A_, B_, bmv, bnv, Kv)                                          \
  f32x4 acc[4][4] = {};                                                            \
  const int nt = (Kv) >> 6;                                                        \
  STAGE_T(A_, B_, bmv, bnv, Kv, 0, 0);                                             \
  asm volatile("s_waitcnt vmcnt(0)" ::: "memory");                                 \
  __builtin_amdgcn_s_barrier();                                                    \
  for (int t = 0; t < nt; ++t) {                                                   \
    if (t + 1 < nt) STAGE_T(A_, B_, bmv, bnv, Kv, t + 1, (t + 1) & 1);             \
    const char* bA = (const char*)sA + (t & 1) * 16384;                            \
    const char* bB = (const char*)sB + (t & 1) * 16384;                            \
    bf16x8 af[4][2], bfr[4][2];                                                    \
    _Pragma("unroll")                                                              \
    for (int mi = 0; mi < 4; ++mi) {                                               \
      int row = wr + mi * 16 + l16;                                                \
      _Pragma("unroll")                                                            \
      for (int kk = 0; kk < 2; ++kk) {                                             \
        int sl = (kk * 4 + lg) ^ (row & 7);                                        \
        af[mi][kk] = *(const bf16x8*)(bA + row * 128 + sl * 16);                   \
      }                                                                            \
    }                                                                              \
    _Pragma("unroll")                                                              \
    for (int ni = 0; ni < 4; ++ni) {                                               \
      int row = wc + ni * 16 + l16;                                                \
      _Pragma("unroll")                                                            \
      for (int kk = 0; kk < 2; ++kk) {                                             \
        int sl = (kk * 4 + lg) ^ (row & 7);                                        \
        bfr[ni][kk] = *(const bf16x8*)(bB + row * 128 + sl * 16);                  \
      }                                                                            \
    }                                                                              \
    _Pragma("unroll")                                                              \
    for (int kk = 0; kk < 2; ++kk)                                                 \
      _Pragma("unroll")                                                            \
      for (int mi = 0; mi < 4; ++mi)                                               \
        _Pragma("unroll")                                                          \
        for (int ni = 0; ni < 4; ++ni)                                             \
          acc[mi][ni] = __builtin_amdgcn_mfma_f32_16x16x32_bf16(                   \
              af[mi][kk], bfr[ni][kk], acc[mi][ni], 0, 0, 0);                      \
    asm volatile("s_waitcnt vmcnt(0)" ::: "memory");                               \
    __builtin_amdgcn_s_barrier();                                                  \
  }

// ---------------- fused multi-output GEMM: out[j] = A @ Bt[j]^T + bias[j] ----------------
struct QKV3 {
  const __bf16* Bt[3];
  const float* bias[3];
  __bf16* out[3];
};

template<int NW>
__global__ __launch_bounds__(256) void gemmqkv_kernel(
    const __bf16* __restrict__ A, QKV3 args, int K)
{
  __shared__ __align__(16) __bf16 smem[32768];   // 64 KB: sA dbuf | sB dbuf; reused as sC
  __bf16* const sA = smem;
  __bf16* const sB = smem + 16384;
  __bf16* const sC = smem;                       // 128 x 136 bf16 epilogue tile
  const int tid = threadIdx.x, lane = tid & 63, wv = tid >> 6;
  const int l16 = lane & 15, lg = lane >> 4;
  const int wr = (wv >> 1) * 64, wc = (wv & 1) * 64;

  const int nblk = gridDim.x, cpx = nblk >> 3, orig = blockIdx.x;
  const int wg  = (orig & 7) * cpx + (orig >> 3);       // bijective XCD swizzle
  const int r_  = wg / (2 * NW), rem = wg % (2 * NW);
  const int j   = rem >> 1;
  const int bm  = r_ * 128, bn = (rem & 1) * 128;
  const __bf16* __restrict__ Bt = args.Bt[j];

  GEMM64_PIPE(A, Bt, bm, bn, K)

  const float* bias = args.bias[j];
  __bf16* C = args.out[j];
#pragma unroll
  for (int mi = 0; mi < 4; ++mi)
#pragma unroll
    for (int ni = 0; ni < 4; ++ni) {
      int cl = wc + ni * 16 + l16;
      float bval = bias[bn + cl];
      int r0 = wr + mi * 16 + lg * 4;
#pragma unroll
      for (int i = 0; i < 4; ++i)
        sC[(r0 + i) * 136 + cl] = (__bf16)(acc[mi][ni][i] + bval);
    }
  __syncthreads();
#pragma unroll
  for (int it = 0; it < 8; ++it) {
    int idx = it * 256 + tid;
    int r = idx >> 4, seg = idx & 15;
    bf16x8 cv = *(const bf16x8*)&sC[r * 136 + seg * 8];
    *(bf16x8*)(C + (size_t)(bm + r) * 256 + bn + seg * 8) = cv;
  }
}

// ---------------- O-proj GEMM: C = R + relu(A @ Bt^T + bias) ----------------
__global__ __launch_bounds__(256) void gemm128_kernel(
    const __bf16* __restrict__ A, const __bf16* __restrict__ Bt,
    const float* __restrict__ bias, const __bf16* __restrict__ R,
    __bf16* __restrict__ C, int K)
{
  __shared__ __align__(16) __bf16 smem[32768];
  __bf16* const sA = smem;
  __bf16* const sB = smem + 16384;
  __bf16* const sC = smem;
  const int tid = threadIdx.x, lane = tid & 63, wv = tid >> 6;
  const int l16 = lane & 15, lg = lane >> 4;
  const int wr = (wv >> 1) * 64, wc = (wv & 1) * 64;

  const int nblk = gridDim.x, cpx = nblk >> 3, orig = blockIdx.x;
  const int wg  = (orig & 7) * cpx + (orig >> 3);
  const int bm  = (wg >> 1) * 128, bn = (wg & 1) * 128;

  GEMM64_PIPE(A, Bt, bm, bn, K)

  const float* __restrict__ biasp = bias;
#pragma unroll
  for (int mi = 0; mi < 4; ++mi)
#pragma unroll
    for (int ni = 0; ni < 4; ++ni) {
      int cl = wc + ni * 16 + l16;
      float bval = biasp[bn + cl];
      int r0 = wr + mi * 16 + lg * 4;
#pragma unroll
      for (int i = 0; i < 4; ++i)
        sC[(r0 + i) * 136 + cl] = (__bf16)fmaxf(acc[mi][ni][i] + bval, 0.f);
    }
  __syncthreads();
#pragma unroll
  for (int it = 0; it < 8; ++it) {
    int idx = it * 256 + tid;
    int r = idx >> 4, seg = idx & 15;
    bf16x8 cv = *(const bf16x8*)&sC[r * 136 + seg * 8];
    bf16x8 rv = *(const bf16x8*)(R + (size_t)(bm + r) * 256 + bn + seg * 8);
    bf16x8 ov;
#pragma unroll
    for (int i = 0; i < 8; ++i)
      ov[i] = (__bf16)((float)rv[i] + (float)cv[i]);
    *(bf16x8*)(C + (size_t)(bm + r) * 256 + bn + seg * 8) = ov;
  }
}

// ---------------- small-M GEMM (MLP): fp32 B inline-converted, reg-prefetch pipelined ----
template<int EPI, bool OUTF32>
__global__ __launch_bounds__(256) void gemm_kernel(
    const __bf16* __restrict__ A, const float* __restrict__ B,
    const float* __restrict__ bias, const __bf16* __restrict__ R,
    void* __restrict__ Cv, int M, int N, int K)
{
  __shared__ __bf16 sA[64][40];
  __shared__ __bf16 sB[64][40];
  const int tid  = threadIdx.x;
  const int lane = tid & 63;
  const int wv   = tid >> 6;
  const int wr   = (wv >> 1) * 32;
  const int wc   = (wv & 1) * 32;
  const int bm   = blockIdx.x * 64;
  const int bn   = blockIdx.y * 64;
  const int l16  = lane & 15;
  const int lk8  = (lane >> 4) * 8;

  const int a_r = tid >> 2, a_c = (tid & 3) * 8;
  const int b_c = tid & 63, b_k = (tid >> 6) * 8;

  f32x4 acc[2][2] = {};

  // register prefetch of K-step 0
  bf16x8 av = *(const bf16x8*)(A + (size_t)(bm + a_r) * K + a_c);
  float bvf[8];
#pragma unroll
  for (int j = 0; j < 8; ++j)
    bvf[j] = B[(size_t)(b_k + j) * N + bn + b_c];

  for (int k0 = 0; k0 < K; k0 += 32) {
    // commit prefetched tile to LDS
    *(bf16x8*)&sA[a_r][a_c] = av;
    bf16x8 bb;
#pragma unroll
    for (int j = 0; j < 8; ++j) bb[j] = (__bf16)bvf[j];
    *(bf16x8*)&sB[b_c][b_k] = bb;
    __syncthreads();
    // issue next K-step's global loads; latency hides under compute below
    if (k0 + 32 < K) {
      av = *(const bf16x8*)(A + (size_t)(bm + a_r) * K + k0 + 32 + a_c);
#pragma unroll
      for (int j = 0; j < 8; ++j)
        bvf[j] = B[(size_t)(k0 + 32 + b_k + j) * N + bn + b_c];
    }
    bf16x8 af0 = *(const bf16x8*)&sA[wr + l16][lk8];
    bf16x8 af1 = *(const bf16x8*)&sA[wr + 16 + l16][lk8];
    bf16x8 bf0 = *(const bf16x8*)&sB[wc + l16][lk8];
    bf16x8 bf1 = *(const bf16x8*)&sB[wc + 16 + l16][lk8];
    acc[0][0] = __builtin_amdgcn_mfma_f32_16x16x32_bf16(af0, bf0, acc[0][0], 0, 0, 0);
    acc[0][1] = __builtin_amdgcn_mfma_f32_16x16x32_bf16(af0, bf1, acc[0][1], 0, 0, 0);
    acc[1][0] = __builtin_amdgcn_mfma_f32_16x16x32_bf16(af1, bf0, acc[1][0], 0, 0, 0);
    acc[1][1] = __builtin_amdgcn_mfma_f32_16x16x32_bf16(af1, bf1, acc[1][1], 0, 0, 0);
    __syncthreads();
  }

#pragma unroll
  for (int mi = 0; mi < 2; ++mi)
#pragma unroll
    for (int ni = 0; ni < 2; ++ni) {
      int col = bn + wc + ni * 16 + l16;
      float bval = bias[col];
      int row0 = bm + wr + mi * 16 + (lane >> 4) * 4;
#pragma unroll
      for (int i = 0; i < 4; ++i) {
        int row = row0 + i;
        float v = acc[mi][ni][i] + bval;
        if (EPI == 1) v = fmaxf(v, 0.f);
        if (EPI == 2) v = (float)R[(size_t)row * N + col] + fmaxf(v, 0.f);
        if (OUTF32) ((float*)Cv)[(size_t)row * N + col] = v;
        else        ((__bf16*)Cv)[(size_t)row * N + col] = (__bf16)v;
      }
    }
}

// ---------------- fused SAB attention (R13/R14 artifact, final) ----------------
__global__ __launch_bounds__(512, 2) void attn_sab_kernel(
    __bf16* __restrict__ Q, const __bf16* __restrict__ Kb, const __bf16* __restrict__ Vb)
{
  __shared__ __align__(16) __bf16 sK[128][72];
  __shared__ __align__(16) __bf16 sV[64][136];
  __shared__ __align__(16) __bf16 sP[8][16][72];

  const int orig = blockIdx.x;                 // 512 blocks
  const int wg   = (orig & 7) * 64 + (orig >> 3);
  const int qh   = wg & 1;
  const int pair = wg >> 1;                    // 0..255
  const int head = pair & 3;
  const int item = pair >> 2;

  const int tid  = threadIdx.x;
  const int lane = tid & 63;
  const int wv   = tid >> 6;
  const int l16  = lane & 15;
  const int lg   = lane >> 4;
  const size_t base = (size_t)item * (512 * 256) + (size_t)head * 64;
  const int qrow0 = qh * 256 + wv * 32;

  // hoisted Q fragments: [qb][d-half]
  bf16x8 aq[2][2];
#pragma unroll
  for (int qb = 0; qb < 2; ++qb) {
    const size_t qrow = base + (size_t)(qrow0 + qb * 16 + l16) * 256;
    aq[qb][0] = *(const bf16x8*)(Q + qrow + lg * 8);
    aq[qb][1] = *(const bf16x8*)(Q + qrow + 32 + lg * 8);
  }

  f32x4 acco[2][4] = {};
  float lsum[2] = {0.f, 0.f};

  const int kr  = tid >> 3, kc8 = (tid & 7) * 8;
  const int vch = tid & 63, vk8 = (tid >> 6) * 8;

  bf16x8 kreg[2], vreg[2];

#define LOADC(cc) do {                                                             \
    _Pragma("unroll")                                                              \
    for (int p = 0; p < 2; ++p) {                                                  \
      kreg[p] = *(const bf16x8*)(Kb + base + (size_t)((cc)*128 + p*64 + kr)*256 + kc8); \
      bf16x8 vv;                                                                   \
      _Pragma("unroll")                                                            \
      for (int jj = 0; jj < 8; ++jj)                                               \
        vv[jj] = Vb[base + (size_t)((cc)*128 + p*64 + vk8 + jj)*256 + vch];        \
      vreg[p] = vv;                                                                \
    } } while (0)

  LOADC(0);

  for (int c = 0; c < 4; ++c) {
    if (c) __syncthreads();                    // all waves done reading prev chunk
#pragma unroll
    for (int p = 0; p < 2; ++p) {
      *(bf16x8*)&sK[p * 64 + kr][kc8] = kreg[p];
      *(bf16x8*)&sV[vch][p * 64 + vk8] = vreg[p];
    }
    __syncthreads();
    if (c < 3) LOADC(c + 1);                   // overlaps with compute below

#pragma unroll
    for (int half = 0; half < 2; ++half) {
      // K-frags and V-frags for this 64-key half: loaded once, reused by both q-tiles
      bf16x8 kf0[4], kf1[4];
#pragma unroll
      for (int st = 0; st < 4; ++st) {
        int krl = half * 64 + st * 16 + l16;
        kf0[st] = *(const bf16x8*)&sK[krl][lg * 8];
        kf1[st] = *(const bf16x8*)&sK[krl][32 + lg * 8];
      }
      bf16x8 vf[2][4];
#pragma unroll
      for (int kk = 0; kk < 2; ++kk)
#pragma unroll
        for (int vt = 0; vt < 4; ++vt)
          vf[kk][vt] = *(const bf16x8*)&sV[vt * 16 + l16][half * 64 + kk * 32 + lg * 8];

#pragma unroll
      for (int qb = 0; qb < 2; ++qb) {
        f32x4 s[4];
#pragma unroll
        for (int st = 0; st < 4; ++st) {
          f32x4 z = {};
          s[st] = __builtin_amdgcn_mfma_f32_16x16x32_bf16(kf0[st], aq[qb][0], z, 0, 0, 0);
        }
#pragma unroll
        for (int st = 0; st < 4; ++st)
          s[st] = __builtin_amdgcn_mfma_f32_16x16x32_bf16(kf1[st], aq[qb][1], s[st], 0, 0, 0);
#pragma unroll
        for (int st = 0; st < 4; ++st) {
          bf16x4 pv4;
          float ls = 0.f;
#pragma unroll
          for (int i = 0; i < 4; ++i) {
            float p = __builtin_amdgcn_exp2f(s[st][i] * LOG2E_O16);
            ls += p;
            pv4[i] = (__bf16)p;
          }
          lsum[qb] += ls;
          *(bf16x4*)&sP[wv][l16][st * 16 + lg * 4] = pv4;
        }
#pragma unroll
        for (int kk = 0; kk < 2; ++kk) {
          bf16x8 ap = *(const bf16x8*)&sP[wv][l16][kk * 32 + lg * 8];
#pragma unroll
          for (int vt = 0; vt < 4; ++vt)
            acco[qb][vt] = __builtin_amdgcn_mfma_f32_16x16x32_bf16(ap, vf[kk][vt], acco[qb][vt], 0, 0, 0);
        }
      }
    }
  }
#undef LOADC

#pragma unroll
  for (int qb = 0; qb < 2; ++qb) {
    float t = lsum[qb];
    t += __shfl_xor(t, 16, 64);
    t += __shfl_xor(t, 32, 64);
#pragma unroll
    for (int i = 0; i < 4; ++i) {
      float tot = __shfl(t, lg * 4 + i, 64);
      float inv = 1.0f / tot;
      int row = qrow0 + qb * 16 + lg * 4 + i;
#pragma unroll
      for (int vt = 0; vt < 4; ++vt) {
        size_t idx = base + (size_t)row * 256 + vt * 16 + l16;
        Q[idx] = (__bf16)((float)Q[idx] + acco[qb][vt][i] * inv);
      }
    }
  }
}

// ---------------- PMA decode attention v2: grid 256 = (item, quarter) ----------------
__global__ __launch_bounds__(256) void pma_attn_kernel(
    const float* __restrict__ S, const float* __restrict__ wq,
    const float* __restrict__ bq, const __bf16* __restrict__ Kb,
    const __bf16* __restrict__ Vb, __bf16* __restrict__ Opma)
{
  __shared__ float sS[256];
  __shared__ float sq[256];
  __shared__ float sP[512];      // this head's scores
  __shared__ float wsum[4];
  __shared__ float sl0;
  __shared__ float red[256];

  const int item = blockIdx.x >> 2;
  const int quarter = blockIdx.x & 3;
  const int h = quarter >> 1;
  const int t = threadIdx.x;
  const int lane = t & 63, wv = t >> 6;

  sS[t] = S[t];
  __syncthreads();
  {
    float acc = bq[t];
#pragma unroll 8
    for (int k = 0; k < 256; ++k) acc += sS[k] * wq[k * 256 + t];
    sq[t] = acc;
  }
  __syncthreads();

  // QK for head h: 512 keys, 2 per thread
#pragma unroll
  for (int rep = 0; rep < 2; ++rep) {
    int key = rep * 256 + t;
    const __bf16* kr = Kb + ((size_t)item * 512 + key) * 256 + h * 128;
    float s = 0.f;
#pragma unroll
    for (int d8 = 0; d8 < 128; d8 += 8) {
      bf16x8 kv = *(const bf16x8*)(kr + d8);
#pragma unroll
      for (int j = 0; j < 8; ++j) s += sq[h * 128 + d8 + j] * (float)kv[j];
    }
    sP[key] = __builtin_amdgcn_exp2f(s * LOG2E_O16);
  }
  __syncthreads();

  // denominator: wave shfl reduce + cross-wave
  {
    float p = sP[t] + sP[t + 256];
#pragma unroll
    for (int m = 1; m < 64; m <<= 1) p += __shfl_xor(p, m, 64);
    if (lane == 0) wsum[wv] = p;
  }
  __syncthreads();
  if (t == 0) sl0 = 1.0f / (wsum[0] + wsum[1] + wsum[2] + wsum[3]);

  // PV: 64 channels (quarter*64 + chl), 4 threads/channel x 128 keys
  {
    const int chl = t & 63, seg = t >> 6;
    const int ch = quarter * 64 + chl;
    const __bf16* vp = Vb + ((size_t)item * 512 + seg * 128) * 256 + ch;
    float acc = 0.f;
#pragma unroll 4
    for (int k = 0; k < 128; ++k)
      acc += sP[seg * 128 + k] * (float)vp[(size_t)k * 256];
    red[t] = acc;
  }
  __syncthreads();
  if (t < 64) {
    int ch = quarter * 64 + t;
    float a = red[t] + red[t + 64] + red[t + 128] + red[t + 192];
    Opma[item * 256 + ch] = (__bf16)(sq[ch] + a * sl0);
  }
}

// ---------------- launch ----------------
extern "C" void kernel_launch(void* const* d_in, const int* in_sizes, int n_in,
                              void* d_out, int out_size, void* d_ws, size_t ws_size,
                              hipStream_t stream)
{
  const size_t XSZ = (size_t)64 * 512 * 256;
  if (ws_size < 4 * XSZ * sizeof(__bf16) + (4u << 20)) return;

  const float* rep = (const float*)d_in[0];
  const float* GA  = (const float*)d_in[1];

  __bf16* X    = (__bf16*)d_ws;
  __bf16* Qb   = X  + XSZ;
  __bf16* Kb   = Qb + XSZ;
  __bf16* Vb   = Kb + XSZ;
  __bf16* wT   = Vb + XSZ;                 // 10 x 256x256 bf16 (row = out ch, col = k)
  __bf16* Opma = wT + 10 * 65536;
  __bf16* O2   = Opma + 64 * 256;
  __bf16* H1   = O2 + 64 * 256;
  __bf16* H2   = H1 + 64 * 512;

  WPtrs wp;
  for (int s = 0; s < 2; ++s)
    for (int j = 0; j < 4; ++j)
      wp.w[s * 4 + j] = (const float*)d_in[2 + s * 8 + j * 2];
  wp.w[8] = (const float*)d_in[21];
  wp.w[9] = (const float*)d_in[23];
  wconv_kernel<<<dim3(16, 10), 256, 0, stream>>>(wp, wT);

  scale_kernel<<<8192, 256, 0, stream>>>(rep, GA, X);

  for (int sab = 0; sab < 2; ++sab) {
    QKV3 a;
    a.Bt[0] = wT + (size_t)(sab * 4 + 0) * 65536;
    a.Bt[1] = wT + (size_t)(sab * 4 + 1) * 65536;
    a.Bt[2] = wT + (size_t)(sab * 4 + 2) * 65536;
    a.bias[0] = (const float*)d_in[2 + sab * 8 + 1];
    a.bias[1] = (const float*)d_in[2 + sab * 8 + 3];
    a.bias[2] = (const float*)d_in[2 + sab * 8 + 5];
    a.out[0] = Qb; a.out[1] = Kb; a.out[2] = Vb;
    gemmqkv_kernel<3><<<1536, 256, 0, stream>>>(X, a, 256);
    attn_sab_kernel<<<512, 512, 0, stream>>>(Qb, Kb, Vb);
    gemm128_kernel<<<512, 256, 0, stream>>>(Qb, wT + (size_t)(sab * 4 + 3) * 65536,
        (const float*)d_in[2 + sab * 8 + 7], Qb, X, 256);
  }

  {
    QKV3 a;
    a.Bt[0] = wT + (size_t)8 * 65536;
    a.Bt[1] = wT + (size_t)9 * 65536;
    a.Bt[2] = wT;  // unused
    a.bias[0] = (const float*)d_in[22];
    a.bias[1] = (const float*)d_in[24];
    a.bias[2] = (const float*)d_in[22];  // unused
    a.out[0] = Kb; a.out[1] = Vb; a.out[2] = Kb;  // slot 2 unused
    gemmqkv_kernel<2><<<1024, 256, 0, stream>>>(X, a, 256);
  }
  pma_attn_kernel<<<256, 256, 0, stream>>>((const float*)d_in[18], (const float*)d_in[19],
      (const float*)d_in[20], Kb, Vb, Opma);
  gemm_kernel<2, false><<<dim3(1, 4), 256, 0, stream>>>(Opma, (const float*)d_in[25],
      (const float*)d_in[26], Opma, O2, 64, 256, 256);
  gemm_kernel<1, false><<<dim3(1, 8), 256, 0, stream>>>(O2, (const float*)d_in[27],
      (const float*)d_in[28], nullptr, H1, 64, 512, 256);
  gemm_kernel<1, false><<<dim3(1, 8), 256, 0, stream>>>(H1, (const float*)d_in[29],
      (const float*)d_in[30], nullptr, H2, 64, 512, 512);
  gemm_kernel<0, true><<<dim3(1, 4), 256, 0, stream>>>(H2, (const float*)d_in[31],
      (const float*)d_in[32], nullptr, (float*)d_out, 64, 256, 512);
}